// Round 1
// baseline (109.071 us; speedup 1.0000x reference)
//
#include <hip/hip_runtime.h>

// ---------------------------------------------------------------------------
// out[i] = exp(cumsum_{j<k} log1p(-beta_j)),  k = clip(round(t[i]), 0, 1000)
// beta_j = a + d*j is linear, so clog(k) = -(S1 + S2/2 + S3/3) + O(1e-5) is a
// closed-form degree-4 polynomial in k (power sums), evaluated by Horner.
// Truncation + float Horner error <= ~1e-5 absolute in exp(clog); threshold 2e-2.
//
// R4 post-mortem: nontemporal load/store + grid-stride regressed 109->114 us
// (confounded: two changes at once).
// R5 (this round): timed region = 2x 256MiB poison fills (82.8 us, harness) +
// kernel (~25.9 us = 5.18 TB/s vs 6.29 TB/s copy ceiling). Theory: one-shot
// threads (1 load, ~100cy dependent chain, 1 store, die) cap per-wave MLP at 1
// and pay 8x wave turnover. Fix: 2048 blocks x 256 thr, 8 float4/thread,
// batched loads-then-stores (8 KB in flight/wave). Plain loads/stores (no NT)
// to isolate the batching variable. Predict kernel ~21.5 us, dur_us ~104.
// ---------------------------------------------------------------------------
namespace {
constexpr double a_  = 1e-4;
constexpr double d_  = (20.0 / 1000.0 - 1e-4) / 999.0;

constexpr double A1d = (a_ - d_ / 2.0)
                     + (a_ * a_ - a_ * d_ + d_ * d_ / 6.0) / 2.0
                     + (a_ * a_ * a_ - 1.5 * a_ * a_ * d_ + 0.5 * a_ * d_ * d_) / 3.0;
constexpr double A2d = d_ / 2.0
                     + (a_ * d_ - d_ * d_ / 2.0) / 2.0
                     + (1.5 * a_ * a_ * d_ - 1.5 * a_ * d_ * d_ + 0.25 * d_ * d_ * d_) / 3.0;
constexpr double A3d = d_ * d_ / 6.0
                     + (a_ * d_ * d_ - 0.5 * d_ * d_ * d_) / 3.0;
constexpr double A4d = d_ * d_ * d_ / 12.0;

constexpr float A1 = (float)A1d;
constexpr float A2 = (float)A2d;
constexpr float A3 = (float)A3d;
constexpr float A4 = (float)A4d;
constexpr float LOG2E = 1.4426950408889634f;

constexpr int TPB    = 256;
constexpr int UNROLL = 8;            // float4s per thread per tile
constexpr int TILE   = TPB * UNROLL; // float4s per block-tile
}

__device__ __forceinline__ float alpha_bar(float v) {
    float k = __builtin_rintf(v);             // v_rndne_f32 = jnp.round semantics
    k = fminf(fmaxf(k, 0.0f), 1000.0f);
    float p = fmaf(k, A4, A3);
    p = fmaf(k, p, A2);
    p = fmaf(k, p, A1);
    return exp2f(-k * p * LOG2E);
}

__global__ __launch_bounds__(TPB)
void ddpm_alpha_bar(const float* __restrict__ t,
                    float* __restrict__ out,
                    int n) {
    const int n4 = n >> 2;
    const float4* __restrict__ t4 = (const float4*)t;
    float4*       __restrict__ o4 = (float4*)out;

    for (long long base = (long long)blockIdx.x * TILE; base < n4;
         base += (long long)gridDim.x * TILE) {
        const long long idx0 = base + threadIdx.x;

        if (base + TILE <= (long long)n4) {
            // Fast path: whole tile in bounds. Issue all loads first (8 KB of
            // MLP per wave), then compute+store as vmcnt drains.
            float4 v[UNROLL];
            #pragma unroll
            for (int j = 0; j < UNROLL; ++j)
                v[j] = t4[idx0 + j * TPB];
            #pragma unroll
            for (int j = 0; j < UNROLL; ++j) {
                float4 r;
                r.x = alpha_bar(v[j].x);
                r.y = alpha_bar(v[j].y);
                r.z = alpha_bar(v[j].z);
                r.w = alpha_bar(v[j].w);
                o4[idx0 + j * TPB] = r;
            }
        } else {
            #pragma unroll
            for (int j = 0; j < UNROLL; ++j) {
                const long long idx = idx0 + j * TPB;
                if (idx < (long long)n4) {
                    float4 v = t4[idx];
                    float4 r;
                    r.x = alpha_bar(v.x);
                    r.y = alpha_bar(v.y);
                    r.z = alpha_bar(v.z);
                    r.w = alpha_bar(v.w);
                    o4[idx] = r;
                }
            }
        }
    }

    // Scalar tail (n not divisible by 4): rem <= 3 < TPB.
    const int done = (n >> 2) << 2;
    const int rem  = n - done;
    if (blockIdx.x == 0 && (int)threadIdx.x < rem) {
        const int k = done + threadIdx.x;
        out[k] = alpha_bar(t[k]);
    }
}

extern "C" void kernel_launch(void* const* d_in, const int* in_sizes, int n_in,
                              void* d_out, int out_size, void* d_ws, size_t ws_size,
                              hipStream_t stream) {
    const float* t = (const float*)d_in[0];
    float* out     = (float*)d_out;
    const int n    = in_sizes[0];

    const int n4 = n >> 2;
    long long tiles = ((long long)n4 + TILE - 1) / TILE;
    int blocks = (int)(tiles < 2048 ? tiles : 2048);
    if (blocks < 1) blocks = 1;
    ddpm_alpha_bar<<<blocks, TPB, 0, stream>>>(t, out, n);
}